// Round 3
// baseline (531.599 us; speedup 1.0000x reference)
//
#include <hip/hip_runtime.h>
#include <hip/hip_bf16.h>
#include <math.h>

typedef _Float16 half8_t __attribute__((ext_vector_type(8)));
typedef _Float16 half4_t __attribute__((ext_vector_type(4)));
typedef float    floatx4 __attribute__((ext_vector_type(4)));

#define GLOAD16(gp, lp) __builtin_amdgcn_global_load_lds( \
    (const __attribute__((address_space(1))) void*)(gp),  \
    (__attribute__((address_space(3))) void*)(lp), 16, 0, 0)

static constexpr int Bc  = 8;
static constexpr int Tc  = 4096;
static constexpr int Ic  = 1024;     // GEMM K
static constexpr int Hc  = 1024;     // GEMM N
static constexpr int Mc  = Bc * Tc;  // 32768 GEMM rows
static constexpr int NCc = 256;      // scan chunks
static constexpr int Lc  = Tc / NCc; // 16 steps per chunk (== one MFMA m-band)

// ---------------- scan helpers ----------------
__device__ __forceinline__ float sigm(float x) { return 1.0f / (1.0f + __expf(-x)); }
__device__ __forceinline__ float g_fn(float x) { return x >= 0.0f ? x + 0.5f : sigm(x); }
__device__ __forceinline__ void fv_from_kp(float kk, float pp, float& f, float& v)
{
    float ek = __expf(kk);        // e^k
    f = 1.0f / (1.0f + ek);       // sigmoid(-k)
    v = (1.0f - f) * g_fn(pp);    // sigmoid(k) * g(p)
}

// ---------------- fused fp32->fp16 convert (x, Wz, Wh in one launch) ----------------
__global__ __launch_bounds__(256) void cvt_all(
    const float* __restrict__ x,  const float* __restrict__ Wz, const float* __restrict__ Wh,
    _Float16* __restrict__ x16, _Float16* __restrict__ w16z, _Float16* __restrict__ w16h)
{
    const float* src; _Float16* dst; long n, bid, nb;
    if (blockIdx.x < 2048)      { src = x;  dst = x16;  n = (long)Mc * Ic; bid = blockIdx.x;        nb = 2048; }
    else if (blockIdx.x < 2112) { src = Wz; dst = w16z; n = (long)Hc * Ic; bid = blockIdx.x - 2048; nb = 64; }
    else                        { src = Wh; dst = w16h; n = (long)Hc * Ic; bid = blockIdx.x - 2112; nb = 64; }
    long i = (bid * 256 + threadIdx.x) * 4;
    long stride = nb * 256 * 4;
    for (; i < n; i += stride) {
        float4 v = *reinterpret_cast<const float4*>(src + i);
        half4_t h;
        h[0] = (_Float16)v.x; h[1] = (_Float16)v.y;
        h[2] = (_Float16)v.z; h[3] = (_Float16)v.w;
        *reinterpret_cast<half4_t*>(dst + i) = h;
    }
}

// ---------------- fused dual GEMM + local-scan epilogue ----------------
// One block: 128 rows x 128 cols of BOTH outputs. A staged once per K-step.
// 8 waves: wave>>2 selects output (0:k, 1:p); (wave>>1)&1, wave&1 pick 64x64 sub-tile.
// Epilogue: p-waves publish g(p) via LDS; k-waves compute per-chunk (F, S) scan
// composites (chunk = 16 rows = one MFMA m-band) and write Fb/Sb in [B,H,NC] layout.
__global__ __launch_bounds__(512) void dual_gemm_f16(
    const _Float16* __restrict__ A,
    const _Float16* __restrict__ Wz,
    const _Float16* __restrict__ Wh,
    const float* __restrict__ bz,
    const float* __restrict__ bh,
    _Float16* __restrict__ k16,
    _Float16* __restrict__ p16,
    float* __restrict__ Fb,
    float* __restrict__ Sb)
{
    constexpr int BK = 32, K = Ic, N = Hc, NSTEP = K / BK;
    __shared__ __align__(16) _Float16 smem[24576];   // 48 KB
    _Float16* sA  = smem;            // [2][128*32]
    _Float16* sBz = smem + 8192;     // [2][128*32]
    _Float16* sBh = smem + 16384;    // [2][128*32]

    // XCD-chunked swizzle (2048 % 8 == 0 -> bijective): all 8 n-blocks of an
    // A-panel land on one XCD's L2.
    const int bid     = blockIdx.x;
    const int logical = (bid & 7) * 256 + (bid >> 3);
    const int n0 = (logical & 7) * 128;
    const int m0 = (logical >> 3) * 128;

    const int tid  = threadIdx.x;
    const int lane = tid & 63;
    const int wave = tid >> 6;
    const int zsel = wave >> 2;
    const int wr = (wave >> 1) & 1, wc = wave & 1;

    // staging: thread i -> tile row i>>2 (0..127), 8-half chunk i&3
    const int srow = tid >> 2;
    const int schk = (tid & 3) * 8;
    const int soff = srow * BK + schk;
    const _Float16* gA  = A  + (size_t)(m0 + srow) * K + schk;
    const _Float16* gBz = Wz + (size_t)(n0 + srow) * K + schk;
    const _Float16* gBh = Wh + (size_t)(n0 + srow) * K + schk;

    // MFMA fragment addressing (16x16x32: row=lane&15, k-chunk=(lane>>4)*8)
    const int lrow = lane & 15;
    const int kch  = (lane >> 4) * 8;
    const _Float16* sBsel = zsel ? sBh : sBz;
    const int aoff = (wr * 64 + lrow) * BK + kch;
    const int boff = (wc * 64 + lrow) * BK + kch;

    floatx4 acc[4][4];
#pragma unroll
    for (int m = 0; m < 4; m++)
#pragma unroll
        for (int n = 0; n < 4; n++) acc[m][n] = (floatx4){0.f, 0.f, 0.f, 0.f};

    // prologue: stage tile 0 into buf 0
    GLOAD16(gA,  &sA [soff]);
    GLOAD16(gBz, &sBz[soff]);
    GLOAD16(gBh, &sBh[soff]);
    __syncthreads();

    int buf = 0;
    for (int ki = 0; ki < NSTEP; ki++) {
        if (ki + 1 < NSTEP) {            // prefetch next tile into other buffer
            const int kt = (ki + 1) * BK;
            const int po = (buf ^ 1) * 4096 + soff;
            GLOAD16(gA  + kt, &sA [po]);
            GLOAD16(gBz + kt, &sBz[po]);
            GLOAD16(gBh + kt, &sBh[po]);
        }
        const half8_t* rA = (const half8_t*)&sA[buf * 4096 + aoff];
        const half8_t* rB = (const half8_t*)(sBsel + buf * 4096 + boff);
        half8_t af[4], bf[4];
#pragma unroll
        for (int m = 0; m < 4; m++) af[m] = rA[m * 64];   // +16 rows = 16*32/8 half8s
#pragma unroll
        for (int n = 0; n < 4; n++) bf[n] = rB[n * 64];
#pragma unroll
        for (int m = 0; m < 4; m++)
#pragma unroll
            for (int n = 0; n < 4; n++)
                acc[m][n] = __builtin_amdgcn_mfma_f32_16x16x32_f16(af[m], bf[n], acc[m][n], 0, 0, 0);
        __syncthreads();   // drains vmcnt (prefetch landed) + all LDS reads done
        buf ^= 1;
    }

    // ---- epilogue (D row=(lane>>4)*4+reg, col=lane&15 per 16x16 fragment) ----
    const int r0 = (lane >> 4) * 4;
    _Float16* gpL = smem;            // [128][128] fp16, 32 KB overlay (LDS free now)

    if (zsel) {                      // p-waves: store p16, publish g(p)
#pragma unroll
        for (int n = 0; n < 4; n++) {
            const int colL = wc * 64 + n * 16 + lrow;
            const float bv = bh[n0 + colL];
#pragma unroll
            for (int m = 0; m < 4; m++) {
                const int rowL = wr * 64 + m * 16 + r0;
#pragma unroll
                for (int r = 0; r < 4; r++) {
                    _Float16 ph = (_Float16)(acc[m][n][r] + bv);
                    p16[(size_t)(m0 + rowL + r) * N + (n0 + colL)] = ph;
                    gpL[(rowL + r) * 128 + colL] = (_Float16)g_fn((float)ph);
                }
            }
        }
    }
    __syncthreads();
    if (!zsel) {                     // k-waves: store k16, compute chunk (F,S)
        const int b    = m0 >> 12;   // m0 / Tc
        const int trow = m0 & 4095;
#pragma unroll
        for (int n = 0; n < 4; n++) {
            const int colL = wc * 64 + n * 16 + lrow;
            const int col  = n0 + colL;
            const float bv = bz[col];
#pragma unroll
            for (int m = 0; m < 4; m++) {
                const int rowL = wr * 64 + m * 16 + r0;
                float Fl = 1.0f, Sl = 0.0f;
#pragma unroll
                for (int r = 0; r < 4; r++) {     // 4 contiguous t-rows (this lane's run)
                    _Float16 kh = (_Float16)(acc[m][n][r] + bv);
                    k16[(size_t)(m0 + rowL + r) * N + col] = kh;
                    float f = 1.0f / (1.0f + __expf((float)kh));
                    float v = (1.0f - f) * (float)gpL[(rowL + r) * 128 + colL];
                    Sl = fmaf(f, Sl, v);
                    Fl *= f;
                }
                // ordered butterfly compose across the 4 lane-groups (t order = g order)
                float Fp = __shfl_xor(Fl, 16), Sp = __shfl_xor(Sl, 16);
                Sl = (lane & 16) ? fmaf(Sp, Fl, Sl) : fmaf(Sl, Fp, Sp);
                Fl *= Fp;
                Fp = __shfl_xor(Fl, 32); Sp = __shfl_xor(Sl, 32);
                Sl = (lane & 32) ? fmaf(Sp, Fl, Sl) : fmaf(Sl, Fp, Sp);
                Fl *= Fp;
                if (lane < 16) {
                    const int c = (trow + wr * 64 + m * 16) >> 4;   // chunk index
                    const size_t idx = ((size_t)b * Hc + col) * NCc + c;
                    Fb[idx] = Fl; Sb[idx] = Sl;
                }
            }
        }
    }
}

// ---------------- pass B: carry scan over 256 chunks, [B,H,NC] layout ----------------
__global__ __launch_bounds__(128) void scanB(const float* __restrict__ h0p,
                                             const float* __restrict__ Fb,
                                             const float* __restrict__ Sb,
                                             float* __restrict__ Cin)
{
    const int idx = blockIdx.x * 128 + threadIdx.x;  // 0..8191
    const int b = idx >> 10, h = idx & 1023;
    float carry = g_fn(h0p[(size_t)b * Hc + h]);
    const size_t base = ((size_t)b * Hc + h) * NCc;
    for (int c = 0; c < NCc; c += 4) {
        float4 F4 = *reinterpret_cast<const float4*>(Fb + base + c);
        float4 S4 = *reinterpret_cast<const float4*>(Sb + base + c);
        float4 C4;
        C4.x = carry; carry = fmaf(F4.x, carry, S4.x);
        C4.y = carry; carry = fmaf(F4.y, carry, S4.y);
        C4.z = carry; carry = fmaf(F4.z, carry, S4.z);
        C4.w = carry; carry = fmaf(F4.w, carry, S4.w);
        *reinterpret_cast<float4*>(Cin + base + c) = C4;
    }
}

// ---------------- pass C: apply carry, recompute f/v, write h (fp32) ----------------
__global__ __launch_bounds__(128) void scanC(const _Float16* __restrict__ k16,
                                             const _Float16* __restrict__ p16,
                                             const float* __restrict__ Cin,
                                             float* __restrict__ out)
{
    const int b = blockIdx.y, c = blockIdx.x;
    const int h0 = threadIdx.x * 8;
    size_t base = ((size_t)b * Tc + (size_t)c * Lc) * Hc + h0;
    float hr[8];
#pragma unroll
    for (int j = 0; j < 8; j++)
        hr[j] = Cin[((size_t)b * Hc + h0 + j) * NCc + c];
    for (int t = 0; t < Lc; t++) {
        half8_t k8 = *reinterpret_cast<const half8_t*>(k16 + base + (size_t)t * Hc);
        half8_t p8 = *reinterpret_cast<const half8_t*>(p16 + base + (size_t)t * Hc);
#pragma unroll
        for (int j = 0; j < 8; j++) {
            float f, v; fv_from_kp((float)k8[j], (float)p8[j], f, v);
            hr[j] = fmaf(f, hr[j], v);
        }
        *reinterpret_cast<float4*>(out + base + (size_t)t * Hc)     = make_float4(hr[0], hr[1], hr[2], hr[3]);
        *reinterpret_cast<float4*>(out + base + (size_t)t * Hc + 4) = make_float4(hr[4], hr[5], hr[6], hr[7]);
    }
}

// ---------------- launch ----------------
extern "C" void kernel_launch(void* const* d_in, const int* in_sizes, int n_in,
                              void* d_out, int out_size, void* d_ws, size_t ws_size,
                              hipStream_t stream)
{
    const float* x  = (const float*)d_in[0];
    const float* h0 = (const float*)d_in[1];
    const float* Wz = (const float*)d_in[2];
    const float* bz = (const float*)d_in[3];
    const float* Wh = (const float*)d_in[4];
    const float* bh = (const float*)d_in[5];
    float* out = (float*)d_out;

    char* ws = (char*)d_ws;
    // layout (bytes):
    //   x16   @ 0          (64 MB)   [aliased by Cin after GEMM consumes x16]
    //   w16z  @ 67108864   (2 MB)
    //   w16h  @ 69206016   (2 MB)
    //   k16   @ 71303168   (64 MB)
    //   p16   @ 138412032  (64 MB)
    //   Fb    @ 205520896  (8 MB)
    //   Sb    @ 213909504  (8 MB)    high-water 212 MB
    _Float16* x16  = (_Float16*)ws;
    _Float16* w16z = (_Float16*)(ws + 67108864ULL);
    _Float16* w16h = (_Float16*)(ws + 69206016ULL);
    _Float16* k16  = (_Float16*)(ws + 71303168ULL);
    _Float16* p16  = (_Float16*)(ws + 138412032ULL);
    float* Fb  = (float*)(ws + 205520896ULL);
    float* Sb  = (float*)(ws + 213909504ULL);
    float* Cin = (float*)ws;         // aliases x16 (dead after GEMM)

    cvt_all<<<2176, 256, 0, stream>>>(x, Wz, Wh, x16, w16z, w16h);

    dual_gemm_f16<<<2048, 512, 0, stream>>>(x16, w16z, w16h, bz, bh, k16, p16, Fb, Sb);

    scanB<<<64, 128, 0, stream>>>(h0, Fb, Sb, Cin);

    dim3 cgrid(NCc, Bc);             // (256, 8)
    scanC<<<cgrid, 128, 0, stream>>>(k16, p16, Cin, out);
}